// Round 9
// baseline (99.778 us; speedup 1.0000x reference)
//
#include <hip/hip_runtime.h>

typedef __attribute__((ext_vector_type(2))) float f32x2;

#define NS 1024      // N samples
#define MM 64        // M patches
#define CC 4         // C compartments
#define NSTEPS 100
#define CLIPMAX 1e10f

// Broadcast lane k's value to all lanes via v_readlane.
__device__ __forceinline__ float rdlane(float v, int k) {
    return __uint_as_float(__builtin_amdgcn_readlane(__float_as_uint(v), k));
}
// Force a (wave-uniform) value into an SGPR.
__device__ __forceinline__ float sfirst(float v) {
    return __uint_as_float(__builtin_amdgcn_readfirstlane(__float_as_uint(v)));
}

// One wave per sample, barrier-free. r9 changes vs r7:
//  (1) G (the transpose-gathered, scattered-in-global matrix) is staged ONCE
//      into LDS as Gs[j4][lane] float4; the per-step re-reads are conflict-free
//      ds_read_b128 (r2-r8: compiler remat'd these loads from L2/L3 every
//      step -- the dominant ~1100 cyc/step stall).
//  (2) A per-step asm memory clobber makes cross-iteration load remat UNSOUND,
//      so Rrow finally gets (and keeps) VGPR homes -- the residency pin that
//      "+v" ties / +fz adds / num_agpr(0) never achieved.
__global__ __launch_bounds__(64, 1) void metapop_kernel(
    const float* __restrict__ R,     // (NS, MM, MM)
    const float* __restrict__ T,     // (NS, CC, CC)
    const float* __restrict__ rho0,  // (NS, MM, CC)
    const float* __restrict__ beta,  // (NS,)
    float* __restrict__ out)         // (NSTEPS, NS, MM, CC)
{
    const int n    = blockIdx.x;
    const int lane = threadIdx.x;    // 0..63

    __shared__ float4 Gs[MM / 4][MM];   // Gs[j4][i] = G[4j4..4j4+3][i]

    const float* Rn = R + (size_t)n * (MM * MM);

    // ---- Rrow pairs: Rrow[k2] = (R[n,lane,2k2], R[n,lane,2k2+1]) ----
    f32x2 Rrow[32];
    {
        const float4* p4 = (const float4*)(Rn + lane * MM);
        #pragma unroll
        for (int q = 0; q < 16; ++q) {
            float4 v = p4[q];
            Rrow[2*q]   = (f32x2){v.x, v.y};
            Rrow[2*q+1] = (f32x2){v.z, v.w};
        }
    }

    // ---- ntot[lane] = sum_i R[n,i,lane] (coalesced per i; L1/L2-hot) ----
    float nt = 0.f;
    #pragma unroll
    for (int i = 0; i < MM; ++i) nt += Rn[i * MM + lane];
    const float binv = beta[n] / nt;   // lane j holds beta/ntot[j]

    // ---- G[j][lane] = Rt[n,lane,j]*beta/ntot[j] -> LDS, float4-packed by j ----
    // Rt[n,i,j] = R[(i&15)*64+j, (n&15)*4+(i>>4), n>>4]
    {
        const int q     = n >> 4;
        const int a     = ((n & 15) << 2) + (lane >> 4);
        const int sbase = (lane & 15) << 6;
        #pragma unroll
        for (int j4 = 0; j4 < MM / 4; ++j4) {
            float4 g;
            g.x = R[(size_t)(sbase + 4*j4 + 0) * (MM * MM) + a * MM + q] * rdlane(binv, 4*j4 + 0);
            g.y = R[(size_t)(sbase + 4*j4 + 1) * (MM * MM) + a * MM + q] * rdlane(binv, 4*j4 + 1);
            g.z = R[(size_t)(sbase + 4*j4 + 2) * (MM * MM) + a * MM + q] * rdlane(binv, 4*j4 + 2);
            g.w = R[(size_t)(sbase + 4*j4 + 3) * (MM * MM) + a * MM + q] * rdlane(binv, 4*j4 + 3);
            Gs[j4][lane] = g;   // conflict-free b128 write (16 B lane stride)
        }
    }

    // ---- T[n]: wave-uniform -> SGPRs ----
    float tt[CC][CC];
    {
        const float* Tn = T + n * (CC * CC);
        #pragma unroll
        for (int k = 0; k < CC; ++k)
            #pragma unroll
            for (int l = 0; l < CC; ++l)
                tt[k][l] = sfirst(Tn[k * CC + l]);
    }

    // ---- rho0 ----
    float rh[CC];
    {
        float4 v = *(const float4*)(rho0 + (size_t)n * (MM * CC) + lane * CC);
        rh[0] = v.x; rh[1] = v.y; rh[2] = v.z; rh[3] = v.w;
    }

    float* ob = out + (size_t)n * (MM * CC) + lane * CC;
    const size_t stride = (size_t)NS * MM * CC;

    for (int step = 0; step < NSTEPS; ++step) {
        // memory clobber: cross-iteration load remat now unsound -> Rrow gets
        // real VGPR homes; Gs reads stay in-loop (they're the cheap LDS path).
        asm volatile("" ::: "memory");

        // trajectory records PRE-update state; coalesced float4, fire-and-forget
        *(float4*)(ob + (size_t)step * stride) =
            make_float4(rh[0], rh[1], rh[2], rh[3]);

        // phase A (lane = i): p = 1 - prod_j (1 - rho1*G[j][i]); 4 chains,
        // 16x independent conflict-free ds_read_b128 feeding independent fmas
        const float r1 = rh[1];
        float pr0 = 1.f, pr1 = 1.f, pr2 = 1.f, pr3 = 1.f;
        #pragma unroll
        for (int q = 0; q < 4; ++q) {
            float4 gA = Gs[q     ][lane];
            float4 gB = Gs[q +  4][lane];
            float4 gC = Gs[q +  8][lane];
            float4 gD = Gs[q + 12][lane];
            pr0 *= (1.f - r1 * gA.x) * (1.f - r1 * gA.y)
                 * (1.f - r1 * gA.z) * (1.f - r1 * gA.w);
            pr1 *= (1.f - r1 * gB.x) * (1.f - r1 * gB.y)
                 * (1.f - r1 * gB.z) * (1.f - r1 * gB.w);
            pr2 *= (1.f - r1 * gC.x) * (1.f - r1 * gC.y)
                 * (1.f - r1 * gC.z) * (1.f - r1 * gC.w);
            pr3 *= (1.f - r1 * gD.x) * (1.f - r1 * gD.y)
                 * (1.f - r1 * gD.z) * (1.f - r1 * gD.w);
        }
        const float p = 1.f - (pr0 * pr1) * (pr2 * pr3);

        // phase B (lane = j): s = sum_k Rrow[k]*p[k]; readlane broadcast, 4 chains
        float s0 = 0.f, s1 = 0.f, s2 = 0.f, s3 = 0.f;
        #pragma unroll
        for (int k2 = 0; k2 < 8; ++k2) {
            const f32x2 rA = Rrow[k2],      rB = Rrow[k2 + 8];
            const f32x2 rC = Rrow[k2 + 16], rD = Rrow[k2 + 24];
            s0 += rA.x * rdlane(p, 2*k2)      + rA.y * rdlane(p, 2*k2 + 1);
            s1 += rB.x * rdlane(p, 2*k2 + 16) + rB.y * rdlane(p, 2*k2 + 17);
            s2 += rC.x * rdlane(p, 2*k2 + 32) + rC.y * rdlane(p, 2*k2 + 33);
            s3 += rD.x * rdlane(p, 2*k2 + 48) + rD.y * rdlane(p, 2*k2 + 49);
        }
        const float ssum = (s0 + s1) + (s2 + s3);
        const float sr   = (rh[0] + rh[1]) + (rh[2] + rh[3]);
        const float ninf = (1.f - sr) * ssum;

        // phase C (lane-local): rho_new[l] = sum_k rho[k]*T[k,l] (+ninf at l=0)
        float nr[CC];
        #pragma unroll
        for (int l = 0; l < CC; ++l) {
            float v = rh[0] * tt[0][l] + rh[1] * tt[1][l]
                    + rh[2] * tt[2][l] + rh[3] * tt[3][l];
            if (l == 0) v += ninf;
            nr[l] = fminf(fmaxf(v, 0.f), CLIPMAX);
        }
        #pragma unroll
        for (int l = 0; l < CC; ++l) rh[l] = nr[l];
    }
}

extern "C" void kernel_launch(void* const* d_in, const int* in_sizes, int n_in,
                              void* d_out, int out_size, void* d_ws, size_t ws_size,
                              hipStream_t stream) {
    const float* R    = (const float*)d_in[0];
    const float* T    = (const float*)d_in[1];
    const float* rho0 = (const float*)d_in[2];
    const float* beta = (const float*)d_in[3];
    float* out = (float*)d_out;
    hipLaunchKernelGGL(metapop_kernel, dim3(NS), dim3(64), 0, stream,
                       R, T, rho0, beta, out);
}

// Round 10
// 77.613 us; speedup vs baseline: 1.2856x; 1.2856x over previous
//
#include <hip/hip_runtime.h>

typedef __attribute__((ext_vector_type(2))) float f32x2;

#define NS 1024      // N samples
#define MM 64        // M patches
#define CC 4         // C compartments
#define NSTEPS 100
#define CLIPMAX 1e10f

// Broadcast lane k's value to all lanes via v_readlane.
__device__ __forceinline__ float rdlane(float v, int k) {
    return __uint_as_float(__builtin_amdgcn_readlane(__float_as_uint(v), k));
}
// Force a (wave-uniform) value into an SGPR.
__device__ __forceinline__ float sfirst(float v) {
    return __uint_as_float(__builtin_amdgcn_readfirstlane(__float_as_uint(v)));
}

// One wave per sample, barrier-free, fully register-resident state.
// The 9-round lesson assembled:
//  * amdgpu_waves_per_eu(1,1) is the ONLY thing that lifts the VGPR
//    allocator cap (r4: VGPR=132 with it; r3/r7: 80-84 with
//    __launch_bounds__(64,1) alone).
//  * asm "+v" ties then hold Rrow/Gcol in those registers (r4 proof).
//  * __syncthreads() is poison here: its vmcnt(0) drain serializes each
//    step on the trajectory store (r4/r5/r6 losses) -> no barriers, no LDS;
//    p broadcast by v_readlane (r7's best phase B).
//  * packed f32x2 phase A (r7).
extern "C" __global__
__attribute__((amdgpu_flat_work_group_size(64, 64), amdgpu_waves_per_eu(1, 1)))
void metapop_kernel(
    const float* __restrict__ R,     // (NS, MM, MM)
    const float* __restrict__ T,     // (NS, CC, CC)
    const float* __restrict__ rho0,  // (NS, MM, CC)
    const float* __restrict__ beta,  // (NS,)
    float* __restrict__ out)         // (NSTEPS, NS, MM, CC)
{
    const int n    = blockIdx.x;
    const int lane = threadIdx.x;    // 0..63

    const float* Rn = R + (size_t)n * (MM * MM);

    // ---- Rrow pairs: Rrow[k2] = (R[n,lane,2k2], R[n,lane,2k2+1]) ----
    f32x2 Rrow[32];
    {
        const float4* p4 = (const float4*)(Rn + lane * MM);
        #pragma unroll
        for (int q = 0; q < 16; ++q) {
            float4 v = p4[q];
            Rrow[2*q]   = (f32x2){v.x, v.y};
            Rrow[2*q+1] = (f32x2){v.z, v.w};
        }
    }

    // ---- ntot[lane] = sum_i R[n,i,lane] (coalesced per i; L1/L2-hot) ----
    float nt = 0.f;
    #pragma unroll
    for (int i = 0; i < MM; ++i) nt += Rn[i * MM + lane];
    const float binv = beta[n] / nt;   // lane j holds beta/ntot[j]

    // ---- Gcol pairs via the transpose bijection ----
    // Rt[n,i,j] = R[(i&15)*64+j, (n&15)*4+(i>>4), n>>4]
    f32x2 Gcol[32];
    {
        const int q     = n >> 4;
        const int a     = ((n & 15) << 2) + (lane >> 4);
        const int sbase = (lane & 15) << 6;
        #pragma unroll
        for (int j2 = 0; j2 < 32; ++j2) {
            const int j0 = 2 * j2, j1 = 2 * j2 + 1;
            float v0 = R[(size_t)(sbase + j0) * (MM * MM) + a * MM + q];
            float v1 = R[(size_t)(sbase + j1) * (MM * MM) + a * MM + q];
            Gcol[j2] = (f32x2){v0 * rdlane(binv, j0), v1 * rdlane(binv, j1)};
        }
    }

    // ---- PIN state into VGPRs (works only together with waves_per_eu(1,1)) ----
    #pragma unroll
    for (int q = 0; q < 32; ++q) asm volatile("" : "+v"(Rrow[q]));
    #pragma unroll
    for (int q = 0; q < 32; ++q) asm volatile("" : "+v"(Gcol[q]));

    // ---- T[n]: wave-uniform -> SGPRs ----
    float tt[CC][CC];
    {
        const float* Tn = T + n * (CC * CC);
        #pragma unroll
        for (int k = 0; k < CC; ++k)
            #pragma unroll
            for (int l = 0; l < CC; ++l)
                tt[k][l] = sfirst(Tn[k * CC + l]);
    }

    // ---- rho0 ----
    float rh[CC];
    {
        float4 v = *(const float4*)(rho0 + (size_t)n * (MM * CC) + lane * CC);
        rh[0] = v.x; rh[1] = v.y; rh[2] = v.z; rh[3] = v.w;
    }

    float* ob = out + (size_t)n * (MM * CC) + lane * CC;
    const size_t stride = (size_t)NS * MM * CC;

    for (int step = 0; step < NSTEPS; ++step) {
        // trajectory records PRE-update state; coalesced float4, fire-and-forget
        *(float4*)(ob + (size_t)step * stride) =
            make_float4(rh[0], rh[1], rh[2], rh[3]);

        // phase A (lane = i): p = 1 - prod_j (1 - rho1*Gcol[j]); packed, 4 chains
        const float r1  = rh[1];
        const f32x2 r1v = {r1, r1};
        const f32x2 one = {1.f, 1.f};
        f32x2 pa = one, pb = one, pc = one, pd = one;
        #pragma unroll
        for (int j2 = 0; j2 < 8; ++j2) {
            pa *= one - r1v * Gcol[j2];
            pb *= one - r1v * Gcol[j2 + 8];
            pc *= one - r1v * Gcol[j2 + 16];
            pd *= one - r1v * Gcol[j2 + 24];
        }
        const f32x2 pq = (pa * pb) * (pc * pd);
        const float p  = 1.f - pq.x * pq.y;

        // phase B (lane = j): s = sum_k Rrow[k]*p[k]; readlane broadcast, 4 chains
        float s0 = 0.f, s1 = 0.f, s2 = 0.f, s3 = 0.f;
        #pragma unroll
        for (int k2 = 0; k2 < 8; ++k2) {
            const f32x2 rA = Rrow[k2],      rB = Rrow[k2 + 8];
            const f32x2 rC = Rrow[k2 + 16], rD = Rrow[k2 + 24];
            s0 += rA.x * rdlane(p, 2*k2)      + rA.y * rdlane(p, 2*k2 + 1);
            s1 += rB.x * rdlane(p, 2*k2 + 16) + rB.y * rdlane(p, 2*k2 + 17);
            s2 += rC.x * rdlane(p, 2*k2 + 32) + rC.y * rdlane(p, 2*k2 + 33);
            s3 += rD.x * rdlane(p, 2*k2 + 48) + rD.y * rdlane(p, 2*k2 + 49);
        }
        const float ssum = (s0 + s1) + (s2 + s3);
        const float sr   = (rh[0] + rh[1]) + (rh[2] + rh[3]);
        const float ninf = (1.f - sr) * ssum;

        // phase C (lane-local): rho_new[l] = sum_k rho[k]*T[k,l] (+ninf at l=0)
        float nr[CC];
        #pragma unroll
        for (int l = 0; l < CC; ++l) {
            float v = rh[0] * tt[0][l] + rh[1] * tt[1][l]
                    + rh[2] * tt[2][l] + rh[3] * tt[3][l];
            if (l == 0) v += ninf;
            nr[l] = fminf(fmaxf(v, 0.f), CLIPMAX);
        }
        #pragma unroll
        for (int l = 0; l < CC; ++l) rh[l] = nr[l];
    }
}

extern "C" void kernel_launch(void* const* d_in, const int* in_sizes, int n_in,
                              void* d_out, int out_size, void* d_ws, size_t ws_size,
                              hipStream_t stream) {
    const float* R    = (const float*)d_in[0];
    const float* T    = (const float*)d_in[1];
    const float* rho0 = (const float*)d_in[2];
    const float* beta = (const float*)d_in[3];
    float* out = (float*)d_out;
    hipLaunchKernelGGL(metapop_kernel, dim3(NS), dim3(64), 0, stream,
                       R, T, rho0, beta, out);
}